// Round 5
// baseline (100.748 us; speedup 1.0000x reference)
//
#include <hip/hip_runtime.h>
#include <math.h>

#define HF 96
#define WF 192
#define CC 32
#define NPIX (HF*WF)     // 18432
#define DFULL 192
#define DQ 48
#define HO 384
#define WO 768
#define SR2 200          // Rb row: 8 zero-guard floats + 192 data (800 B, 16B mult)

// Cost volume, fused L2 norm, 4w x 8d register tiles, FULL d range.
// Grid (96 rows, 6) x 192 threads: t = y*192+tid in [0,1152) = 48 w-tiles x 24 d-tiles.
// Tile (wt,dt): compute if wt >= 2*dt (600/row), else all-zero fill (552/row).
// Per c: 1 b128 (L) + 3 b128 (R window, 16B-aligned since w0-d0 % 4 == 0) for 32
// outputs. 8-float zero guard before R data makes w<d products exactly 0.
__global__ __launch_bounds__(192) void kcost(const float* __restrict__ L,
                                             const float* __restrict__ R,
                                             float* __restrict__ out) {
    __shared__ __align__(16) float Ls[CC * WF];    // 24 KB
    __shared__ __align__(16) float Rb[CC * SR2];   // 25 KB
    const int h = blockIdx.x;
    const int tid = threadIdx.x;

    // zero guards (32 rows x 8 floats)
    for (int i = tid; i < CC * 8; i += 192) Rb[(i >> 3) * SR2 + (i & 7)] = 0.0f;

    // stage + normalize both rows: one pixel per thread
    {
        const int w = tid;
        float lr[CC], rr[CC];
        float sl = 0.0f, sr = 0.0f;
        #pragma unroll
        for (int c = 0; c < CC; ++c) {
            float lv = L[c * NPIX + h * WF + w];
            float rv = R[c * NPIX + h * WF + w];
            lr[c] = lv; rr[c] = rv;
            sl = fmaf(lv, lv, sl);
            sr = fmaf(rv, rv, sr);
        }
        const float il = 1.0f / sqrtf(sl + 1e-12f);
        const float ir = 1.0f / sqrtf(sr + 1e-12f);
        #pragma unroll
        for (int c = 0; c < CC; ++c) {
            Ls[c * WF + w] = lr[c] * il;
            Rb[c * SR2 + 8 + w] = rr[c] * ir;
        }
    }
    __syncthreads();

    const int t = blockIdx.y * 192 + tid;          // [0,1152), all threads valid
    const int dt = t / 48;                         // 0..23  (d0 = 8*dt, covers d<192)
    const int wt = t - dt * 48;                    // 0..47  (w0 = 4*wt)
    const int w0 = wt * 4, d0 = dt * 8;

    if (wt < 2 * dt) {                             // tile entirely in w < d region
        const float4 z = {0.0f, 0.0f, 0.0f, 0.0f};
        #pragma unroll
        for (int j = 0; j < 8; ++j)
            *(float4*)&out[(d0 + j) * NPIX + h * WF + w0] = z;
        return;
    }

    const int base = w0 - d0;                      // >= 0, multiple of 4, <= 188

    float acc[8][4];
    #pragma unroll
    for (int j = 0; j < 8; ++j)
        #pragma unroll
        for (int i = 0; i < 4; ++i) acc[j][i] = 0.0f;

    #pragma unroll 4
    for (int c = 0; c < CC; ++c) {
        const float4 lq = *(const float4*)&Ls[c * WF + w0];
        const float lv[4] = {lq.x, lq.y, lq.z, lq.w};
        float rr[12];                              // rr[q] = Rn[base + q - 8] (guarded)
        const float4 ra = *(const float4*)&Rb[c * SR2 + base];
        const float4 rb = *(const float4*)&Rb[c * SR2 + base + 4];
        const float4 rc = *(const float4*)&Rb[c * SR2 + base + 8];
        rr[0]=ra.x; rr[1]=ra.y; rr[2]=ra.z; rr[3]=ra.w;
        rr[4]=rb.x; rr[5]=rb.y; rr[6]=rb.z; rr[7]=rb.w;
        rr[8]=rc.x; rr[9]=rc.y; rr[10]=rc.z; rr[11]=rc.w;
        #pragma unroll
        for (int j = 0; j < 8; ++j)
            #pragma unroll
            for (int i = 0; i < 4; ++i)
                acc[j][i] = fmaf(lv[i], rr[8 + i - j], acc[j][i]);  // Rn[w-d], guard->0
    }

    #pragma unroll
    for (int j = 0; j < 8; ++j) {
        float4 v; v.x = acc[j][0]; v.y = acc[j][1]; v.z = acc[j][2]; v.w = acc[j][3];
        *(float4*)&out[(d0 + j) * NPIX + h * WF + w0] = v;
    }
}

// Trilinear upsample + argmax — R3's known-good version (scalar loads; no
// misaligned vector casts). Thread = (h_out, m): 4 output w's {4m+2..4m+5}
// share source cols (m, m+1). Piecewise-linear d-interp: per segment only
// the max-end sample can win the argmax (same fma formula as dense eval).
__global__ __launch_bounds__(256) void kpred(const float* __restrict__ cost,
                                             float* __restrict__ pred) {
    const int mIdx = blockIdx.x * 64 + threadIdx.x;  // 0..255; valid <= 192
    const int h = blockIdx.y * 4 + threadIdx.y;
    if (mIdx > 192) return;
    const int m = mIdx - 1;

    float sh = (float)(2 * h - 3) * 0.125f;
    float fh = sh - floorf(sh);
    int h0 = (int)floorf(sh);
    int h1 = h0 + 1;
    if (h0 < 0)      { h0 = 0; h1 = 0; fh = 0.0f; }
    if (h1 > HF - 1) { h1 = HF - 1;    fh = 0.0f; }
    const float wh0 = 1.0f - fh, wh1 = fh;

    const bool edge = (m < 0) || (m >= WF - 1);
    const int w0 = (m < 0) ? 0 : ((m >= WF - 1) ? WF - 1 : m);
    const int w1 = (m < 0) ? 0 : ((m >= WF - 1) ? WF - 1 : m + 1);

    float fr[4];
    #pragma unroll
    for (int r = 0; r < 4; ++r) fr[r] = edge ? 0.0f : (0.125f + 0.25f * (float)r);

    const int i00 = h0 * WF + w0;
    const int i10 = h1 * WF + w0;
    const int i01 = h0 * WF + w1;
    const int i11 = h1 * WF + w1;

    float bp[4], best[4];
    int bi[4];
    {
        const float* s = cost;
        float q00 = s[i00], q10 = s[i10], q01 = s[i01], q11 = s[i11];
        float A0 = fmaf(wh1, q10, wh0 * q00);
        float A1 = fmaf(wh1, q11, wh0 * q01);
        #pragma unroll
        for (int r = 0; r < 4; ++r) {
            bp[r] = fmaf(fr[r], A1, (1.0f - fr[r]) * A0);
            best[r] = bp[r];
            bi[r] = 0;
        }
    }

    for (int k = 1; k < DQ; ++k) {
        const float* s = cost + k * NPIX;
        float q00 = s[i00], q10 = s[i10], q01 = s[i01], q11 = s[i11];
        float A0 = fmaf(wh1, q10, wh0 * q00);
        float A1 = fmaf(wh1, q11, wh0 * q01);
        #pragma unroll
        for (int r = 0; r < 4; ++r) {
            float b = fmaf(fr[r], A1, (1.0f - fr[r]) * A0);
            float cand; int ci;
            if (b > bp[r]) { cand = fmaf(0.875f, b, 0.125f * bp[r]); ci = 4 * k + 1; }
            else           { cand = fmaf(0.125f, b, 0.875f * bp[r]); ci = 4 * k - 2; }
            if (cand > best[r]) { best[r] = cand; bi[r] = ci; }
            bp[r] = b;
        }
    }
    #pragma unroll
    for (int r = 0; r < 4; ++r)
        if (bp[r] > best[r]) bi[r] = 190;      // d_out = 190,191 fold to slice 47

    float v[4];
    #pragma unroll
    for (int r = 0; r < 4; ++r) v[r] = (float)(bi[r] < 1 ? 1 : bi[r]);

    float* prow = pred + h * WO;
    if (m < 0) {
        float2 o; o.x = v[0]; o.y = v[0];
        *(float2*)&prow[0] = o;                 // w_out 0,1 = col 0
    } else if (m >= WF - 1) {
        float2 o; o.x = v[0]; o.y = v[0];
        *(float2*)&prow[WO - 2] = o;            // w_out 766,767 = col 191
    } else {
        float2 o0; o0.x = v[0]; o0.y = v[1];
        float2 o1; o1.x = v[2]; o1.y = v[3];
        *(float2*)&prow[4 * m + 2] = o0;
        *(float2*)&prow[4 * m + 4] = o1;
    }
}

extern "C" void kernel_launch(void* const* d_in, const int* in_sizes, int n_in,
                              void* d_out, int out_size, void* d_ws, size_t ws_size,
                              hipStream_t stream) {
    const float* L = (const float*)d_in[0];
    const float* R = (const float*)d_in[1];
    float* out = (float*)d_out;                 // cost_init: [192][96][192]
    float* pred = out + DFULL * NPIX;           // pred: [384][768]

    kcost<<<dim3(HF, 6), 192, 0, stream>>>(L, R, out);
    kpred<<<dim3(4, HF), dim3(64, 4), 0, stream>>>(out, pred);
}